// Round 9
// baseline (208.480 us; speedup 1.0000x reference)
//
#include <hip/hip_runtime.h>

// GMDRSSMStep via MFMA: P = x @ W_cat^T (B x 15, padded 16), closed-form epilogue.
// R8 post-mortem: kernel dropped below the 81us harness fills (~45us est), but
// ~2x above the 22us streaming floor -> latency-bound (serial tile loads give
// ~8 outstanding 16B loads/wave; need ~35/wave to cover ~900cy HBM latency at
// 10 B/cy/CU). This version: explicit double-buffered tile prefetch (issue
// tile t+1 loads before pack+MFMA of tile t), 4-wave blocks (grid 1024),
// h-load hoisted above the LDS transpose to overlap the barrier.

using f32x4  = __attribute__((ext_vector_type(4))) float;
using bf16x8 = __attribute__((ext_vector_type(8))) short;

__device__ __forceinline__ short f2bf(float f) {
    union { float f; unsigned u; } v; v.f = f;
    unsigned u = v.u + 0x7fffu + ((v.u >> 16) & 1u);   // round-to-nearest-even
    return (short)(u >> 16);
}

__device__ __forceinline__ bf16x8 pack8(float4 a, float4 b) {
    bf16x8 r;
    r[0] = f2bf(a.x); r[1] = f2bf(a.y); r[2] = f2bf(a.z); r[3] = f2bf(a.w);
    r[4] = f2bf(b.x); r[5] = f2bf(b.y); r[6] = f2bf(b.z); r[7] = f2bf(b.w);
    return r;
}

constexpr int TPB = 256;   // 4 waves/block, 64 rows/wave -> 256 rows/block

__global__ __launch_bounds__(TPB) void gmdr_mfma_kernel(
    const float* __restrict__ h,
    const float* __restrict__ x,
    const float* __restrict__ W_alpha, const float* __restrict__ b_alpha,
    const float* __restrict__ W_a,     const float* __restrict__ b_a,
    const float* __restrict__ W_B,     const float* __restrict__ b_B,
    float* __restrict__ out, int batch)
{
    // P-transpose scratch: [tile T 0..15][m 0..15][n stride 20], tile stride 328
    // words (= 1312 B, 16B-aligned). Write banks 2-way (free), read banks 2-way
    // (free) — same pattern as R8, verified conflict-free there (SQ_LDS_BANK_CONFLICT=0).
    __shared__ float pt[16 * 328];   // 21.0 KB

    const int tid  = threadIdx.x;
    const int lane = tid & 63;
    const int wid  = tid >> 6;
    const int n16  = lane & 15;     // M/N index of this lane's fragments
    const int g    = lane >> 4;     // k-group
    const long wbase = (long)blockIdx.x * 256 + wid * 64;

    // ---- B-fragments: entire 16x128 weight matrix (rows: 3 alpha | 8 a | 4 B | 1 zero)
    bf16x8 wb[4];
#pragma unroll
    for (int s = 0; s < 4; ++s) wb[s] = (bf16x8){};
    {
        const float* wrow = nullptr;
        if (n16 < 3)       wrow = W_alpha + n16 * 128;
        else if (n16 < 11) wrow = W_a + (n16 - 3) * 128;
        else if (n16 < 15) wrow = W_B + (n16 - 11) * 128;
        if (wrow) {
            const float4* wp = reinterpret_cast<const float4*>(wrow);
#pragma unroll
            for (int s = 0; s < 4; ++s)
                wb[s] = pack8(wp[2 * g + 8 * s], wp[2 * g + 8 * s + 1]);
        }
    }

    const float4* __restrict__ X4 = reinterpret_cast<const float4*>(x);

    // per-tile row pointer (clamped; clamped lanes' results are masked at store)
    auto rowptr = [&](int t) {
        long rowA = wbase + t * 16 + n16;
        if (rowA >= batch) rowA = batch - 1;
        return X4 + rowA * 32 + 2 * g;
    };

    f32x4 acc[4];
#pragma unroll
    for (int t = 0; t < 4; ++t) acc[t] = (f32x4){};

    // Double-buffered pipeline: load T0; {load T1, comp T0}; {load T2, comp T1};
    // {load T3, comp T2}; comp T3. Named buffers -> all indices compile-time.
    float4 bufA[8], bufB[8];

#define LOADT(buf, t) { const float4* xp = rowptr(t);                          \
    _Pragma("unroll") for (int s = 0; s < 4; ++s) {                            \
        buf[2*s] = xp[8*s]; buf[2*s+1] = xp[8*s+1]; } }

#define COMPT(buf, t) { _Pragma("unroll") for (int s = 0; s < 4; ++s) {        \
        const bf16x8 af = pack8(buf[2*s], buf[2*s+1]);                         \
        acc[t] = __builtin_amdgcn_mfma_f32_16x16x32_bf16(af, wb[s], acc[t], 0, 0, 0); } }

    LOADT(bufA, 0)
    LOADT(bufB, 1)  COMPT(bufA, 0)
    LOADT(bufA, 2)  COMPT(bufB, 1)
    LOADT(bufB, 3)  COMPT(bufA, 2)
                    COMPT(bufB, 3)
#undef LOADT
#undef COMPT

    // hoist h-load: independent of LDS transpose, overlaps the barrier
    const long row = wbase + lane;   // (lane>>4)*16 + (lane&15) == lane
    float4 hv = make_float4(0.f, 0.f, 0.f, 0.f);
    if (row < batch) hv = reinterpret_cast<const float4*>(h)[row];

    // ---- transpose P through LDS: D[m=(g*4+r)][n=n16] per tile
#pragma unroll
    for (int t = 0; t < 4; ++t)
#pragma unroll
        for (int r = 0; r < 4; ++r)
            pt[(wid * 4 + t) * 328 + (g * 4 + r) * 20 + n16] = acc[t][r];
    __syncthreads();

    if (row < batch) {
        const float4* pr = reinterpret_cast<const float4*>(
            &pt[(wid * 4 + (lane >> 4)) * 328 + (lane & 15) * 20]);
        const float4 pa = pr[0], pb = pr[1], pc = pr[2], pd = pr[3];

        // softmax over 3 kernel-neighborhood logits
        const float l0 = pa.x + b_alpha[0];
        const float l1 = pa.y + b_alpha[1];
        const float l2 = pa.z + b_alpha[2];
        const float m  = fmaxf(l0, fmaxf(l1, l2));
        const float e0 = __expf(l0 - m);
        const float e1 = __expf(l1 - m);
        const float e2 = __expf(l2 - m);
        const float inv = 1.0f / (e0 + e1 + e2);
        const float al0 = e0 * inv, al1 = e1 * inv, al2 = e2 * inv;

        // tanh perturbation coeffs t[i] = 0.1*tanh(p[3+i] + b_a[i])
        const float pv[8] = { pa.w, pb.x, pb.y, pb.z, pb.w, pc.x, pc.y, pc.z };
        float tq[8];
#pragma unroll
        for (int i = 0; i < 8; ++i) {
            const float v = pv[i] + b_a[i];
            tq[i] = (1.0f - 2.0f / (__expf(2.0f * v) + 1.0f)) * 0.1f;
        }

        // A h closed form (verified R4/R6/R8):
        //   [(a0-a2)h0 + a1 h1,  a1 h0 + (a0+a2)h1,  S h2,  S h3]
        // + [(t0+t4)h1, (t1+t5)h2, t2 h0 + t6 h3, t3 h3 + t7 h0]
        const float asum = al0 + al1 + al2;
        const float r0 = (al0 - al2) * hv.x + al1 * hv.y + (tq[0] + tq[4]) * hv.y;
        const float r1 = al1 * hv.x + (al0 + al2) * hv.y + (tq[1] + tq[5]) * hv.z;
        const float r2 = asum * hv.z + tq[2] * hv.x + tq[6] * hv.w;
        const float r3 = asum * hv.w + tq[3] * hv.w + tq[7] * hv.x;

        float4 ov;
        ov.x = r0 + pc.w + b_B[0];
        ov.y = r1 + pd.x + b_B[1];
        ov.z = r2 + pd.y + b_B[2];
        ov.w = r3 + pd.z + b_B[3];
        reinterpret_cast<float4*>(out)[row] = ov;
    }
}

extern "C" void kernel_launch(void* const* d_in, const int* in_sizes, int n_in,
                              void* d_out, int out_size, void* d_ws, size_t ws_size,
                              hipStream_t stream) {
    const float* h       = (const float*)d_in[0];
    const float* x       = (const float*)d_in[1];
    const float* W_alpha = (const float*)d_in[2];
    const float* b_alpha = (const float*)d_in[3];
    const float* W_a     = (const float*)d_in[4];
    const float* b_a     = (const float*)d_in[5];
    const float* W_B     = (const float*)d_in[6];
    const float* b_B     = (const float*)d_in[7];
    float* out = (float*)d_out;

    const int batch = in_sizes[0] / 4;            // h is (B, 4)
    const int grid  = (batch + 255) / 256;        // 256 rows/block -> 1024 blocks

    gmdr_mfma_kernel<<<grid, TPB, 0, stream>>>(
        h, x, W_alpha, b_alpha, W_a, b_a, W_B, b_B, out, batch);
}